// Round 7
// baseline (645.494 us; speedup 1.0000x reference)
//
#include <hip/hip_runtime.h>
#include <math.h>

// Problem constants (match reference)
#define B_      4
#define L_      1024
#define D_INNC  8      // D_IN
#define DMODEL  512
#define DEPTH_  4
#define DINNER  1024
#define DSTATE  16
#define DCONV   4
#define DTRANK  32
#define MTOT    (B_*L_)   // 4096
#define CHUNKS  64
#define CLEN    16        // L_/CHUNKS
#define XPSPLIT 8         // xp GEMM K-splits (K=1024 -> 8 x 128)

typedef float f32x4 __attribute__((ext_vector_type(4)));
typedef short s16x8 __attribute__((ext_vector_type(8)));
typedef unsigned short u16;
typedef unsigned short u16x4v __attribute__((ext_vector_type(4)));

#define GLOBAL_AS __attribute__((address_space(1)))
#define LDS_AS    __attribute__((address_space(3)))

// fp32 -> bf16 round-to-nearest-even
__device__ __forceinline__ u16 f2bf(float v) {
    unsigned b = __float_as_uint(v);
    return (u16)((b + 0x7FFF + ((b >> 16) & 1)) >> 16);
}
__device__ __forceinline__ float bf2f(u16 h) {
    return __uint_as_float((unsigned)h << 16);
}

// ---------------------------------------------------------------------------
// h = x @ in_w^T + in_b  -> bf16 (4096 x 512, K=8)
__global__ __launch_bounds__(256) void in_proj_kernel(
    const float* __restrict__ x, const float* __restrict__ w,
    const float* __restrict__ bias, u16* __restrict__ hb)
{
    int idx = blockIdx.x * 256 + threadIdx.x;
    int m = idx / DMODEL, d = idx % DMODEL;
    const float* xr = x + m * D_INNC;
    const float* wr = w + d * D_INNC;
    float acc = bias[d];
#pragma unroll
    for (int k = 0; k < D_INNC; ++k) acc += xr[k] * wr[k];
    hb[idx] = f2bf(acc);
}

// ---------------------------------------------------------------------------
// One-shot fp32 -> bf16 convert of ALL four GEMM weight arrays.
// Thread i handles 8 consecutive elements of the concatenated range.
// Boundaries (in 8-elem units): Wxz 524288 | Wout 262144 | Wxp 32768 | Wdt 16384.
__global__ __launch_bounds__(256) void wprep_kernel(
    const float* __restrict__ Wxz, const float* __restrict__ Wout,
    const float* __restrict__ Wxp, const float* __restrict__ Wdt,
    u16* __restrict__ wxzb, u16* __restrict__ woutb,
    u16* __restrict__ wxpb, u16* __restrict__ wdtb)
{
    int i = blockIdx.x * 256 + threadIdx.x;     // 0 .. 835583
    const float* src; u16* dst; int off;
    if (i < 524288)      { src = Wxz;  dst = wxzb;  off = i; }
    else if (i < 786432) { src = Wout; dst = woutb; off = i - 524288; }
    else if (i < 819200) { src = Wxp;  dst = wxpb;  off = i - 786432; }
    else                 { src = Wdt;  dst = wdtb;  off = i - 819200; }
    const float* s = src + (size_t)off * 8;
    float4 f0 = *(const float4*)s;
    float4 f1 = *(const float4*)(s + 4);
    float f[8] = {f0.x,f0.y,f0.z,f0.w,f1.x,f1.y,f1.z,f1.w};
    s16x8 hv;
#pragma unroll
    for (int e = 0; e < 8; ++e) hv[e] = (short)f2bf(f[e]);
    *(s16x8*)(dst + (size_t)off * 8) = hv;
}

// ---------------------------------------------------------------------------
// Async-stage one ROWS x 32(u16) K-slice into linear LDS [ROWS][32] via
// global_load_lds width=16. Slot permutation applied on the GLOBAL source
// (linear dest + inverse-swizzled source + swizzled read).
template<int ROWS>
__device__ __forceinline__ void stage_tile(
    const u16* __restrict__ src, int ld, int koff, u16* lds, int t)
{
    const int l = t & 63, w = t >> 6;
    const int r_in = l >> 2, s = l & 3;
#pragma unroll
    for (int p = 0; p < ROWS / 64; ++p) {
        int rb = (p * 4 + w) * 16;            // wave-uniform row base
        int r  = rb + r_in;
        int sw = s ^ ((r ^ (r >> 2)) & 3);    // pre-swizzled source slot
        const u16* g = src + (size_t)r * ld + koff + sw * 8;
        u16* lp = lds + rb * 32;              // uniform per wave
        __builtin_amdgcn_global_load_lds(
            (const GLOBAL_AS void*)g, (LDS_AS void*)lp, 16, 0, 0);
    }
}

// ---------------------------------------------------------------------------
// bf16 MFMA NT GEMM: C[m,n] = sum_k A[m,k]*B[n,k].
// MODE 1: xz epilogue — col<1024: bf16 xcb; col>=1024: silu -> bf16 szb.
// MODE 2: bf16 direct out to C0 (ldc).
// MODE 6: K-split partial — blockIdx.x = split p, kbase = p*K, n0 = 0;
//         fp32 out to C0 + p*MTOT*64 (ld 64). Grid (XPSPLIT, M/BM).
template<int BM, int BN, int MODE>
__global__ __launch_bounds__(256, 2) void gemm_bf16(
    const u16* __restrict__ A, int lda,
    const u16* __restrict__ B, int ldb,
    void* __restrict__ C0, void* __restrict__ C1,
    int ldc, int K)
{
    constexpr int FM = BM / 32;
    constexpr int FN = BN / 32;
    __shared__ __align__(16) u16 As[2][BM * 32];
    __shared__ __align__(16) u16 Bs[2][BN * 32];

    const int t    = threadIdx.x;
    const int lane = t & 63;
    const int w    = t >> 6;
    const int wm   = (w >> 1) * (BM / 2);
    const int wn   = (w & 1) * (BN / 2);
    const int quad = lane >> 4;
    const int l16  = lane & 15;
    const int m0   = blockIdx.y * BM;
    const int n0   = (MODE == 6) ? 0 : blockIdx.x * BN;
    const int kbase= (MODE == 6) ? blockIdx.x * K : 0;
    const int sq   = (quad ^ ((l16 ^ (l16 >> 2)) & 3)) * 8;

    const u16* Abase = A + (size_t)m0 * lda;
    const u16* Bbase = B + (size_t)n0 * ldb;

    f32x4 acc[FM][FN];
#pragma unroll
    for (int i = 0; i < FM; ++i)
#pragma unroll
        for (int j = 0; j < FN; ++j) acc[i][j] = (f32x4){0.f,0.f,0.f,0.f};

    stage_tile<BM>(Abase, lda, kbase, As[0], t);
    stage_tile<BN>(Bbase, ldb, kbase, Bs[0], t);

    int cur = 0;
    for (int kk = 0; kk < K; kk += 32) {
        __syncthreads();                    // drains vmcnt: buf[cur] ready
        int kn = kk + 32;
        if (kn < K) {
            stage_tile<BM>(Abase, lda, kbase + kn, As[cur ^ 1], t);
            stage_tile<BN>(Bbase, ldb, kbase + kn, Bs[cur ^ 1], t);
        }
        s16x8 afr[FM], bfr[FN];
#pragma unroll
        for (int i = 0; i < FM; ++i) {
            int row = wm + i * 16 + l16;
            afr[i] = *(const s16x8*)&As[cur][row * 32 + sq];
        }
#pragma unroll
        for (int j = 0; j < FN; ++j) {
            int row = wn + j * 16 + l16;
            bfr[j] = *(const s16x8*)&Bs[cur][row * 32 + sq];
        }
#pragma unroll
        for (int i = 0; i < FM; ++i)
#pragma unroll
            for (int j = 0; j < FN; ++j)
                acc[i][j] = __builtin_amdgcn_mfma_f32_16x16x32_bf16(afr[i], bfr[j], acc[i][j], 0, 0, 0);
        cur ^= 1;
    }

    // epilogue: C/D layout col=lane&15, row=quad*4+reg
    if constexpr (MODE == 2) {
        u16* C = (u16*)C0;
#pragma unroll
        for (int i = 0; i < FM; ++i)
#pragma unroll
            for (int j = 0; j < FN; ++j) {
                int col = n0 + wn + j*16 + l16;
#pragma unroll
                for (int r = 0; r < 4; ++r) {
                    int row = m0 + wm + i*16 + quad*4 + r;
                    C[(size_t)row * ldc + col] = f2bf(acc[i][j][r]);
                }
            }
    } else if constexpr (MODE == 6) {
        float* P = (float*)C0 + (size_t)blockIdx.x * MTOT * 64;
#pragma unroll
        for (int i = 0; i < FM; ++i)
#pragma unroll
            for (int j = 0; j < FN; ++j) {
                int col = wn + j*16 + l16;
#pragma unroll
                for (int r = 0; r < 4; ++r) {
                    int row = m0 + wm + i*16 + quad*4 + r;
                    P[(size_t)row * 64 + col] = acc[i][j][r];
                }
            }
    } else {    // MODE 1
        u16* xcb = (u16*)C0;
        u16* szb = (u16*)C1;
#pragma unroll
        for (int i = 0; i < FM; ++i)
#pragma unroll
            for (int j = 0; j < FN; ++j) {
                int col = n0 + wn + j*16 + l16;
                bool isz = col >= DINNER;
                int cc = col & (DINNER - 1);
                u16* dst = isz ? szb : xcb;
#pragma unroll
                for (int r = 0; r < 4; ++r) {
                    int row = m0 + wm + i*16 + quad*4 + r;
                    float v = acc[i][j][r];
                    if (isz) v = v / (1.f + __expf(-v));   // silu(z)
                    dst[(size_t)row * DINNER + cc] = f2bf(v);
                }
            }
    }
}

// ---------------------------------------------------------------------------
// Depthwise causal conv (k=4) + bias + SiLU; bf16 in/out. 2 d-channels/thread.
__global__ __launch_bounds__(256) void conv_silu_kernel(
    const u16* __restrict__ xcb, const float* __restrict__ cw,
    const float* __restrict__ cb, u16* __restrict__ ub)
{
    int idx = (blockIdx.x * 256 + threadIdx.x) * 2;   // MTOT*DINNER, even
    int m = idx >> 10;
    int d = idx & (DINNER - 1);
    int l = m & (L_ - 1);

    const float4 w0 = *(const float4*)&cw[d * 4];
    const float4 w1 = *(const float4*)&cw[(d + 1) * 4];
    float a0 = cb[d], a1 = cb[d + 1];
#pragma unroll
    for (int k = 0; k < 4; ++k) {
        int lag = 3 - k;
        if (l >= lag) {
            unsigned v = *(const unsigned*)&xcb[(size_t)(m - lag) * DINNER + d];
            float x0 = bf2f((u16)(v & 0xffff));
            float x1 = bf2f((u16)(v >> 16));
            float wk0 = (&w0.x)[k], wk1 = (&w1.x)[k];
            a0 += x0 * wk0; a1 += x1 * wk1;
        }
    }
    a0 = a0 / (1.f + __expf(-a0));
    a1 = a1 / (1.f + __expf(-a1));
    unsigned pack = (unsigned)f2bf(a0) | ((unsigned)f2bf(a1) << 16);
    *(unsigned*)&ub[idx] = pack;
}

// ---------------------------------------------------------------------------
// Shared phase-0 for the scan kernels: sum XPSPLIT partials into xs[CLEN][64]
// (cols 0..31 = dt_lr fp32, 32..47 = B, 48..63 = C). Bit-identical summation
// order to the old xpred (p = 0..7 sequential).
__device__ __forceinline__ void sum_partials(
    const float* __restrict__ xpart, int mbase, float xs[CLEN][64], int tid)
{
    int idx4 = tid * 4;                     // 16 rows x 64 cols, float4/thread
    int row = idx4 >> 6, col = idx4 & 63;
    float4 s = (float4){0.f, 0.f, 0.f, 0.f};
#pragma unroll
    for (int p = 0; p < XPSPLIT; ++p) {
        float4 v = *(const float4*)&xpart[((size_t)p * MTOT + mbase + row) * 64 + col];
        s.x += v.x; s.y += v.y; s.z += v.z; s.w += v.w;
    }
    *(float4*)&xs[row][col] = s;
}

// dt[m] = softplus(dot32(xs[m][0..31], Wdt[d]) + bdt[d]) for m = 0..15.
// wf[32] = Wdt row (bf16 -> fp32), broadcast LDS reads (conflict-free).
__device__ __forceinline__ void compute_dt(
    const float xs[CLEN][64], const u16* __restrict__ wdtL,
    const float* __restrict__ bdt, int d, float dtv[CLEN])
{
    float wf[32];
    {
        const u16* wrow = wdtL + (size_t)d * DTRANK;
        s16x8 w4[4];
#pragma unroll
        for (int q = 0; q < 4; ++q) w4[q] = *(const s16x8*)(wrow + q * 8);
#pragma unroll
        for (int q = 0; q < 4; ++q)
#pragma unroll
            for (int e = 0; e < 8; ++e) wf[q*8+e] = bf2f((u16)w4[q][e]);
    }
    const float bb = bdt[d];
#pragma unroll
    for (int m = 0; m < CLEN; ++m) {
        float a0 = bb;
#pragma unroll
        for (int q = 0; q < 8; ++q) {
            float4 xv = *(const float4*)&xs[m][q*4];
            a0 += xv.x*wf[q*4] + xv.y*wf[q*4+1] + xv.z*wf[q*4+2] + xv.w*wf[q*4+3];
        }
        dtv[m] = (a0 > 20.f) ? a0 : log1pf(__expf(a0));
    }
}

// ---------------------------------------------------------------------------
// Scan pass 1 (fused): partial-sum + dt compute + local chunk scan.
// Grid: B_*CHUNKS*(DINNER/256) = 1024 blocks.
__global__ __launch_bounds__(256) void scan1_kernel(
    const u16* __restrict__ ub, const float* __restrict__ xpart,
    const u16* __restrict__ wdtL, const float* __restrict__ bdt,
    const float* __restrict__ A_log,
    u16* __restrict__ hfinal, float* __restrict__ dsum)
{
    __shared__ float xs[CLEN][64];
    const int blk  = blockIdx.x;              // b*256 + c*4 + dblk
    const int dblk = blk & 3;
    const int c    = (blk >> 2) & (CHUNKS - 1);
    const int b    = blk >> 8;
    const int d    = dblk * 256 + threadIdx.x;
    const int mbase = b * L_ + c * CLEN;

    sum_partials(xpart, mbase, xs, threadIdx.x);
    float A[16];
    {
        float4 a4[4];
#pragma unroll
        for (int q = 0; q < 4; ++q) a4[q] = *(const float4*)&A_log[d * 16 + q * 4];
        const float* af = (const float*)a4;
#pragma unroll
        for (int s = 0; s < 16; ++s) A[s] = -__expf(af[s]);
    }
    __syncthreads();

    float dtv[CLEN];
    compute_dt(xs, wdtL, bdt, d, dtv);

    float h[16];
#pragma unroll
    for (int s = 0; s < 16; ++s) h[s] = 0.f;
    float dts = 0.f;

#pragma unroll
    for (int t0 = 0; t0 < CLEN; t0 += 8) {
        float u8[8];
#pragma unroll
        for (int j = 0; j < 8; ++j)
            u8[j] = bf2f(ub[(size_t)(mbase + t0 + j) * DINNER + d]);
#pragma unroll
        for (int j = 0; j < 8; ++j) {
            float dtvj = dtv[t0 + j], dtu = dtvj * u8[j];
            dts += dtvj;
            float Bt[16];
#pragma unroll
            for (int q = 0; q < 4; ++q)
                *(float4*)&Bt[q*4] = *(const float4*)&xs[t0 + j][32 + q*4];
#pragma unroll
            for (int s = 0; s < 16; ++s) {
                float dA = __expf(dtvj * A[s]);
                h[s] = dA * h[s] + dtu * Bt[s];
            }
        }
    }
    size_t base = ((size_t)(b * CHUNKS + c) * DINNER + d) * 16;
    s16x8 p0, p1;
#pragma unroll
    for (int s = 0; s < 8; ++s) { p0[s] = (short)f2bf(h[s]); p1[s] = (short)f2bf(h[s+8]); }
    *(s16x8*)&hfinal[base]     = p0;
    *(s16x8*)&hfinal[base + 8] = p1;
    dsum[(size_t)(b * CHUNKS + c) * DINNER + d] = dts;
}

// Pass 2: sequential chunk fix-up (bf16 states, fp32 math). Unchanged.
__global__ __launch_bounds__(256) void scan2_kernel(
    u16* __restrict__ hfinal, const float* __restrict__ dsum,
    const float* __restrict__ A_log)
{
    int t = blockIdx.x * 256 + threadIdx.x;   // 65536 = B_*DINNER*DSTATE
    int s = t & 15, d = (t >> 4) & (DINNER - 1), b = t >> 14;
    float As = -__expf(A_log[d * DSTATE + s]);
    float h = 0.f;
    for (int c0 = 0; c0 < CHUNKS; c0 += 8) {
        float hf8[8], dts8[8];
#pragma unroll
        for (int j = 0; j < 8; ++j) {
            int c = c0 + j;
            size_t i = (size_t)(b * CHUNKS + c) * DINNER + d;
            dts8[j] = dsum[i];
            hf8[j]  = bf2f(hfinal[i * 16 + s]);
        }
#pragma unroll
        for (int j = 0; j < 8; ++j) {
            int c = c0 + j;
            size_t idx = ((size_t)(b * CHUNKS + c) * DINNER + d) * 16 + s;
            hfinal[idx] = f2bf(h);
            h = __expf(As * dts8[j]) * h + hf8[j];
        }
    }
}

// Pass 3 (fused): partial-sum + dt recompute + seeded scan; y written bf16.
__global__ __launch_bounds__(256) void scan3_kernel(
    const u16* __restrict__ szb, const u16* __restrict__ ub,
    const float* __restrict__ xpart,
    const u16* __restrict__ wdtL, const float* __restrict__ bdt,
    const float* __restrict__ A_log, const float* __restrict__ Dp,
    const u16* __restrict__ hstart, u16* __restrict__ yb)
{
    __shared__ float xs[CLEN][64];
    const int blk  = blockIdx.x;
    const int dblk = blk & 3;
    const int c    = (blk >> 2) & (CHUNKS - 1);
    const int b    = blk >> 8;
    const int d    = dblk * 256 + threadIdx.x;
    const int mbase = b * L_ + c * CLEN;

    sum_partials(xpart, mbase, xs, threadIdx.x);
    float A[16];
    {
        float4 a4[4];
#pragma unroll
        for (int q = 0; q < 4; ++q) a4[q] = *(const float4*)&A_log[d * 16 + q * 4];
        const float* af = (const float*)a4;
#pragma unroll
        for (int s = 0; s < 16; ++s) A[s] = -__expf(af[s]);
    }
    const float Dval = Dp[d];
    __syncthreads();

    float dtv[CLEN];
    compute_dt(xs, wdtL, bdt, d, dtv);

    float h[16];
    {
        size_t base = ((size_t)(b * CHUNKS + c) * DINNER + d) * 16;
        s16x8 p0 = *(const s16x8*)&hstart[base];
        s16x8 p1 = *(const s16x8*)&hstart[base + 8];
#pragma unroll
        for (int s = 0; s < 8; ++s) { h[s] = bf2f((u16)p0[s]); h[s+8] = bf2f((u16)p1[s]); }
    }

#pragma unroll
    for (int t0 = 0; t0 < CLEN; t0 += 8) {
        float u8[8], sz8[8];
#pragma unroll
        for (int j = 0; j < 8; ++j) {
            int m = mbase + t0 + j;
            u8[j]  = bf2f(ub [(size_t)m * DINNER + d]);
            sz8[j] = bf2f(szb[(size_t)m * DINNER + d]);
        }
#pragma unroll
        for (int j = 0; j < 8; ++j) {
            float dtvj = dtv[t0 + j], dtu = dtvj * u8[j];
            float Bt[16], Ct[16];
#pragma unroll
            for (int q = 0; q < 4; ++q) {
                *(float4*)&Bt[q*4] = *(const float4*)&xs[t0 + j][32 + q*4];
                *(float4*)&Ct[q*4] = *(const float4*)&xs[t0 + j][48 + q*4];
            }
            float yv = 0.f;
#pragma unroll
            for (int s = 0; s < 16; ++s) {
                float dA = __expf(dtvj * A[s]);
                h[s] = dA * h[s] + dtu * Bt[s];
                yv += h[s] * Ct[s];
            }
            int m = mbase + t0 + j;
            yb[(size_t)m * DINNER + d] = f2bf((yv + u8[j] * Dval) * sz8[j]);
        }
    }
}

// ---------------------------------------------------------------------------
// Final LayerNorm over DMODEL=512, reading bf16 h.
__global__ __launch_bounds__(256) void ln_kernel(
    const u16* __restrict__ hb, const float* __restrict__ g,
    const float* __restrict__ bta, float* __restrict__ out)
{
    int m = blockIdx.x;
    size_t base = (size_t)m * DMODEL;
    int t = threadIdx.x;
    float v0 = bf2f(hb[base + t]);
    float v1 = bf2f(hb[base + t + 256]);
    float sum = v0 + v1, sq = v0*v0 + v1*v1;
#pragma unroll
    for (int off = 32; off; off >>= 1) {
        sum += __shfl_down(sum, off);
        sq  += __shfl_down(sq,  off);
    }
    __shared__ float ls[4], lq[4];
    int w = t >> 6;
    if ((t & 63) == 0) { ls[w] = sum; lq[w] = sq; }
    __syncthreads();
    sum = ls[0] + ls[1] + ls[2] + ls[3];
    sq  = lq[0] + lq[1] + lq[2] + lq[3];
    float mu  = sum * (1.f / DMODEL);
    float var = sq * (1.f / DMODEL) - mu * mu;
    float rs  = rsqrtf(var + 1e-5f);
    out[base + t]       = (v0 - mu) * rs * g[t]       + bta[t];
    out[base + t + 256] = (v1 - mu) * rs * g[t + 256] + bta[t + 256];
}

// ---------------------------------------------------------------------------
extern "C" void kernel_launch(void* const* d_in, const int* in_sizes, int n_in,
                              void* d_out, int out_size, void* d_ws, size_t ws_size,
                              hipStream_t stream)
{
    const float* x      = (const float*)d_in[0];
    const float* in_w   = (const float*)d_in[1];
    const float* in_b   = (const float*)d_in[2];
    const float* W_xz   = (const float*)d_in[3];
    const float* conv_w = (const float*)d_in[4];
    const float* conv_b = (const float*)d_in[5];
    const float* W_xp   = (const float*)d_in[6];
    const float* W_dt   = (const float*)d_in[7];
    const float* b_dt   = (const float*)d_in[8];
    const float* A_log  = (const float*)d_in[9];
    const float* D_par  = (const float*)d_in[10];
    const float* W_out  = (const float*)d_in[11];
    const float* ln_g   = (const float*)d_in[12];
    const float* ln_b   = (const float*)d_in[13];
    float* out = (float*)d_out;

    // Workspace layout (floats), total ~16.9 M floats = 68 MB.
    float* ws      = (float*)d_ws;
    float* hbF     = ws;                    // 1 M   : hb bf16 (2M u16)
    float* hfinF   = hbF    + 1048576;      // 2 M   : hfinal/hstart bf16 (4M u16, CHUNKS=64)
    float* xcbF    = hfinF  + 2097152;      // 2 M   : xc bf16
    float* szbF    = xcbF   + 2097152;      // 2 M   : silu(z) bf16
    float* ubF     = szbF   + 2097152;      // 2 M   : u bf16
    float* ybF     = ubF    + 2097152;      // 2 M   : y bf16
    float* wxzF    = ybF    + 2097152;      // 2 M   : Wxz bf16, all layers
    float* woutF   = wxzF   + 2097152;      // 1 M   : Wout bf16, all layers
    float* wxpF    = woutF  + 1048576;      // 128 K : Wxp bf16, all layers
    float* wdtF    = wxpF   + 131072;       // 64 K  : Wdt bf16, all layers
    float* dsum    = wdtF   + 65536;        // 256 K : per-chunk dt sums fp32
    float* xpart   = dsum   + 262144;       // 2 M   : xp K-split partials fp32 (8 x 4096 x 64)

    u16* hb     = (u16*)hbF;
    u16* hfinal = (u16*)hfinF;
    u16* xcb  = (u16*)xcbF;
    u16* szb  = (u16*)szbF;
    u16* ub   = (u16*)ubF;
    u16* yb   = (u16*)ybF;
    u16* wxzb  = (u16*)wxzF;
    u16* woutb = (u16*)woutF;
    u16* wxpb  = (u16*)wxpF;
    u16* wdtb  = (u16*)wdtF;

    // One-time weight prep (single dispatch: 835584 threads / 3264 blocks).
    wprep_kernel<<<3264, 256, 0, stream>>>(W_xz, W_out, W_xp, W_dt,
                                           wxzb, woutb, wxpb, wdtb);

    in_proj_kernel<<<MTOT*DMODEL/256, 256, 0, stream>>>(x, in_w, in_b, hb);

    for (int layer = 0; layer < DEPTH_; ++layer) {
        const float* cw    = conv_w + (size_t)layer * DINNER * DCONV;
        const float* cb    = conv_b + (size_t)layer * DINNER;
        const float* bdt   = b_dt   + (size_t)layer * DINNER;
        const float* Alog  = A_log  + (size_t)layer * DINNER * DSTATE;
        const float* Dp    = D_par  + (size_t)layer * DINNER;
        const u16* wxzL    = wxzb  + (size_t)layer * 2048 * DMODEL;
        const u16* woutL   = woutb + (size_t)layer * DMODEL * DINNER;
        const u16* wxpL    = wxpb  + (size_t)layer * 64 * DINNER;
        const u16* wdtL    = wdtb  + (size_t)layer * DINNER * DTRANK;

        // xz GEMM (K=512), fused epilogue: bf16 xc + bf16 silu(z)
        gemm_bf16<128,128,1><<<dim3(2048/128, MTOT/128), 256, 0, stream>>>(
            hb, DMODEL, wxzL, DMODEL, xcb, szb, 0, DMODEL);
        // u = silu(conv(xc) + cb)
        conv_silu_kernel<<<MTOT*DINNER/2/256, 256, 0, stream>>>(xcb, cw, cb, ub);
        // xp GEMM K-split: partials (8 splits x K=128), grid 512 blocks
        gemm_bf16<64,64,6><<<dim3(XPSPLIT, MTOT/64), 256, 0, stream>>>(
            ub, DINNER, wxpL, DINNER, xpart, nullptr, 0, DINNER/XPSPLIT);
        // fused scans: partial-sum + dt compute inlined; no xpred / dt GEMM
        scan1_kernel<<<B_*CHUNKS*(DINNER/256), 256, 0, stream>>>(
            ub, xpart, wdtL, bdt, Alog, hfinal, dsum);
        scan2_kernel<<<(B_*DINNER*DSTATE)/256, 256, 0, stream>>>(hfinal, dsum, Alog);
        scan3_kernel<<<B_*CHUNKS*(DINNER/256), 256, 0, stream>>>(
            szb, ub, xpart, wdtL, bdt, Alog, Dp, hfinal, yb);
        // h = y @ Wout^T (K=1024), 64x64 tile, direct bf16 epilogue
        gemm_bf16<64,64,2><<<dim3(DMODEL/64, MTOT/64), 256, 0, stream>>>(
            yb, DINNER, woutL, DINNER, hb, nullptr, DMODEL, DINNER);
    }

    ln_kernel<<<MTOT, 256, 0, stream>>>(hb, ln_g, ln_b, out);
}

// Round 8
// 596.383 us; speedup vs baseline: 1.0823x; 1.0823x over previous
//
#include <hip/hip_runtime.h>
#include <math.h>

// Problem constants (match reference)
#define B_      4
#define L_      1024
#define D_INNC  8      // D_IN
#define DMODEL  512
#define DEPTH_  4
#define DINNER  1024
#define DSTATE  16
#define DCONV   4
#define DTRANK  32
#define MTOT    (B_*L_)   // 4096
#define CHUNKS  64
#define CLEN    16        // L_/CHUNKS
#define XPSPLIT 8         // xp GEMM K-splits (K=1024 -> 8 x 128)

typedef float f32x4 __attribute__((ext_vector_type(4)));
typedef short s16x8 __attribute__((ext_vector_type(8)));
typedef unsigned short u16;
typedef unsigned short u16x4v __attribute__((ext_vector_type(4)));

#define GLOBAL_AS __attribute__((address_space(1)))
#define LDS_AS    __attribute__((address_space(3)))

// fp32 -> bf16 round-to-nearest-even
__device__ __forceinline__ u16 f2bf(float v) {
    unsigned b = __float_as_uint(v);
    return (u16)((b + 0x7FFF + ((b >> 16) & 1)) >> 16);
}
__device__ __forceinline__ float bf2f(u16 h) {
    return __uint_as_float((unsigned)h << 16);
}

// ---------------------------------------------------------------------------
// h = x @ in_w^T + in_b  -> bf16 (4096 x 512, K=8)
__global__ __launch_bounds__(256) void in_proj_kernel(
    const float* __restrict__ x, const float* __restrict__ w,
    const float* __restrict__ bias, u16* __restrict__ hb)
{
    int idx = blockIdx.x * 256 + threadIdx.x;
    int m = idx / DMODEL, d = idx % DMODEL;
    const float* xr = x + m * D_INNC;
    const float* wr = w + d * D_INNC;
    float acc = bias[d];
#pragma unroll
    for (int k = 0; k < D_INNC; ++k) acc += xr[k] * wr[k];
    hb[idx] = f2bf(acc);
}

// ---------------------------------------------------------------------------
// One-shot fp32 -> bf16 convert of ALL four GEMM weight arrays.
// Boundaries (in 8-elem units): Wxz 524288 | Wout 262144 | Wxp 32768 | Wdt 16384.
__global__ __launch_bounds__(256) void wprep_kernel(
    const float* __restrict__ Wxz, const float* __restrict__ Wout,
    const float* __restrict__ Wxp, const float* __restrict__ Wdt,
    u16* __restrict__ wxzb, u16* __restrict__ woutb,
    u16* __restrict__ wxpb, u16* __restrict__ wdtb)
{
    int i = blockIdx.x * 256 + threadIdx.x;     // 0 .. 835583
    const float* src; u16* dst; int off;
    if (i < 524288)      { src = Wxz;  dst = wxzb;  off = i; }
    else if (i < 786432) { src = Wout; dst = woutb; off = i - 524288; }
    else if (i < 819200) { src = Wxp;  dst = wxpb;  off = i - 786432; }
    else                 { src = Wdt;  dst = wdtb;  off = i - 819200; }
    const float* s = src + (size_t)off * 8;
    float4 f0 = *(const float4*)s;
    float4 f1 = *(const float4*)(s + 4);
    float f[8] = {f0.x,f0.y,f0.z,f0.w,f1.x,f1.y,f1.z,f1.w};
    s16x8 hv;
#pragma unroll
    for (int e = 0; e < 8; ++e) hv[e] = (short)f2bf(f[e]);
    *(s16x8*)(dst + (size_t)off * 8) = hv;
}

// ---------------------------------------------------------------------------
// Async-stage one ROWS x 32(u16) K-slice into linear LDS [ROWS][32] via
// global_load_lds width=16. Slot permutation applied on the GLOBAL source
// (linear dest + inverse-swizzled source + swizzled read).
template<int ROWS>
__device__ __forceinline__ void stage_tile(
    const u16* __restrict__ src, int ld, int koff, u16* lds, int t)
{
    const int l = t & 63, w = t >> 6;
    const int r_in = l >> 2, s = l & 3;
#pragma unroll
    for (int p = 0; p < ROWS / 64; ++p) {
        int rb = (p * 4 + w) * 16;            // wave-uniform row base
        int r  = rb + r_in;
        int sw = s ^ ((r ^ (r >> 2)) & 3);    // pre-swizzled source slot
        const u16* g = src + (size_t)r * ld + koff + sw * 8;
        u16* lp = lds + rb * 32;              // uniform per wave
        __builtin_amdgcn_global_load_lds(
            (const GLOBAL_AS void*)g, (LDS_AS void*)lp, 16, 0, 0);
    }
}

// ---------------------------------------------------------------------------
// bf16 MFMA NT GEMM: C[m,n] = sum_k A[m,k]*B[n,k].
// OPERANDS SWAPPED in the MFMA (mfma(b,a)): D frag maps to
//   m = l16 (lane&15), n = quad*4 + reg   [C/D layout symmetry]
// so each lane owns 4 CONSECUTIVE output columns of one row per fragment ->
// packed 8B (bf16 modes) / 16B (fp32 mode) coalesced stores, 4x fewer
// store instructions than the old per-element scatter.
// MODE 1: xz epilogue — col<1024: bf16 xcb; col>=1024: silu -> bf16 szb.
// MODE 2: bf16 direct out to C0 (ldc).
// MODE 4: dt epilogue — softplus(acc + bdt[col]) -> bf16 C0 (ldc).
// MODE 6: K-split partial — blockIdx.x = split p, kbase = p*K, n0 = 0;
//         fp32 out to C0 + p*MTOT*64 (ld 64). Grid (XPSPLIT, M/BM).
template<int BM, int BN, int MODE>
__global__ __launch_bounds__(256, 2) void gemm_bf16(
    const u16* __restrict__ A, int lda,
    const u16* __restrict__ B, int ldb,
    void* __restrict__ C0, void* __restrict__ C1,
    int ldc, int K)
{
    constexpr int FM = BM / 32;
    constexpr int FN = BN / 32;
    __shared__ __align__(16) u16 As[2][BM * 32];
    __shared__ __align__(16) u16 Bs[2][BN * 32];

    const int t    = threadIdx.x;
    const int lane = t & 63;
    const int w    = t >> 6;
    const int wm   = (w >> 1) * (BM / 2);
    const int wn   = (w & 1) * (BN / 2);
    const int quad = lane >> 4;
    const int l16  = lane & 15;
    const int m0   = blockIdx.y * BM;
    const int n0   = (MODE == 6) ? 0 : blockIdx.x * BN;
    const int kbase= (MODE == 6) ? blockIdx.x * K : 0;
    const int sq   = (quad ^ ((l16 ^ (l16 >> 2)) & 3)) * 8;

    const u16* Abase = A + (size_t)m0 * lda;
    const u16* Bbase = B + (size_t)n0 * ldb;

    f32x4 acc[FM][FN];
#pragma unroll
    for (int i = 0; i < FM; ++i)
#pragma unroll
        for (int j = 0; j < FN; ++j) acc[i][j] = (f32x4){0.f,0.f,0.f,0.f};

    stage_tile<BM>(Abase, lda, kbase, As[0], t);
    stage_tile<BN>(Bbase, ldb, kbase, Bs[0], t);

    int cur = 0;
    for (int kk = 0; kk < K; kk += 32) {
        __syncthreads();                    // drains vmcnt: buf[cur] ready
        int kn = kk + 32;
        if (kn < K) {
            stage_tile<BM>(Abase, lda, kbase + kn, As[cur ^ 1], t);
            stage_tile<BN>(Bbase, ldb, kbase + kn, Bs[cur ^ 1], t);
        }
        s16x8 afr[FM], bfr[FN];
#pragma unroll
        for (int i = 0; i < FM; ++i) {
            int row = wm + i * 16 + l16;
            afr[i] = *(const s16x8*)&As[cur][row * 32 + sq];
        }
#pragma unroll
        for (int j = 0; j < FN; ++j) {
            int row = wn + j * 16 + l16;
            bfr[j] = *(const s16x8*)&Bs[cur][row * 32 + sq];
        }
#pragma unroll
        for (int i = 0; i < FM; ++i)
#pragma unroll
            for (int j = 0; j < FN; ++j)
                acc[i][j] = __builtin_amdgcn_mfma_f32_16x16x32_bf16(bfr[j], afr[i], acc[i][j], 0, 0, 0);
        cur ^= 1;
    }

    // epilogue (swapped-operand layout): frag(i,j): m = m0+wm+i*16+l16,
    // n = n0+wn+j*16+quad*4 + r  -> one packed store per fragment.
    if constexpr (MODE == 2) {
        u16* C = (u16*)C0;
#pragma unroll
        for (int i = 0; i < FM; ++i) {
            int m = m0 + wm + i*16 + l16;
#pragma unroll
            for (int j = 0; j < FN; ++j) {
                int nb = n0 + wn + j*16 + quad*4;
                u16x4v o;
#pragma unroll
                for (int r = 0; r < 4; ++r) o[r] = f2bf(acc[i][j][r]);
                *(u16x4v*)&C[(size_t)m * ldc + nb] = o;
            }
        }
    } else if constexpr (MODE == 6) {
        float* P = (float*)C0 + (size_t)blockIdx.x * MTOT * 64;
#pragma unroll
        for (int i = 0; i < FM; ++i) {
            int m = m0 + wm + i*16 + l16;
#pragma unroll
            for (int j = 0; j < FN; ++j) {
                int nb = wn + j*16 + quad*4;
                float4 o;
                o.x = acc[i][j][0]; o.y = acc[i][j][1];
                o.z = acc[i][j][2]; o.w = acc[i][j][3];
                *(float4*)&P[(size_t)m * 64 + nb] = o;
            }
        }
    } else if constexpr (MODE == 4) {
        u16* dtb_ = (u16*)C0;
        const float* bdt = (const float*)C1;
#pragma unroll
        for (int i = 0; i < FM; ++i) {
            int m = m0 + wm + i*16 + l16;
#pragma unroll
            for (int j = 0; j < FN; ++j) {
                int nb = n0 + wn + j*16 + quad*4;
                float4 bb4 = *(const float4*)&bdt[nb];
                u16x4v o;
#pragma unroll
                for (int r = 0; r < 4; ++r) {
                    float v = acc[i][j][r] + (&bb4.x)[r];
                    float sp = (v > 20.f) ? v : log1pf(__expf(v));
                    o[r] = f2bf(sp);
                }
                *(u16x4v*)&dtb_[(size_t)m * ldc + nb] = o;
            }
        }
    } else {    // MODE 1
        u16* xcb = (u16*)C0;
        u16* szb = (u16*)C1;
#pragma unroll
        for (int i = 0; i < FM; ++i) {
            int m = m0 + wm + i*16 + l16;
#pragma unroll
            for (int j = 0; j < FN; ++j) {
                int nb = n0 + wn + j*16 + quad*4;
                bool isz = nb >= DINNER;
                int cc = nb & (DINNER - 1);
                u16* dst = isz ? szb : xcb;
                u16x4v o;
#pragma unroll
                for (int r = 0; r < 4; ++r) {
                    float v = acc[i][j][r];
                    if (isz) v = v / (1.f + __expf(-v));   // silu(z)
                    o[r] = f2bf(v);
                }
                *(u16x4v*)&dst[(size_t)m * DINNER + cc] = o;
            }
        }
    }
}

// ---------------------------------------------------------------------------
// Sum XPSPLIT fp32 partials -> dt_lr bf16 (cols 0..31) + xdbl fp32 (cols 32..63).
// One float4 of columns per thread. Grid: MTOT*16/256 = 256 blocks.
__global__ __launch_bounds__(256) void xpred_kernel(
    const float* __restrict__ part, u16* __restrict__ dtlr,
    float* __restrict__ xd)
{
    int tid = blockIdx.x * 256 + threadIdx.x;   // MTOT*16
    int m = tid >> 4, c4 = (tid & 15) * 4;
    float s0 = 0.f, s1 = 0.f, s2 = 0.f, s3 = 0.f;
#pragma unroll
    for (int p = 0; p < XPSPLIT; ++p) {
        float4 v = *(const float4*)&part[((size_t)p * MTOT + m) * 64 + c4];
        s0 += v.x; s1 += v.y; s2 += v.z; s3 += v.w;
    }
    if (c4 < 32) {
        u16x4v o;
        o[0] = f2bf(s0); o[1] = f2bf(s1); o[2] = f2bf(s2); o[3] = f2bf(s3);
        *(u16x4v*)&dtlr[(size_t)m * 32 + c4] = o;
    } else {
        float4 o; o.x = s0; o.y = s1; o.z = s2; o.w = s3;
        *(float4*)&xd[(size_t)m * 64 + c4] = o;
    }
}

// ---------------------------------------------------------------------------
// Depthwise causal conv (k=4) + bias + SiLU; bf16 in/out. 2 d-channels/thread.
__global__ __launch_bounds__(256) void conv_silu_kernel(
    const u16* __restrict__ xcb, const float* __restrict__ cw,
    const float* __restrict__ cb, u16* __restrict__ ub)
{
    int idx = (blockIdx.x * 256 + threadIdx.x) * 2;   // MTOT*DINNER, even
    int m = idx >> 10;
    int d = idx & (DINNER - 1);
    int l = m & (L_ - 1);

    const float4 w0 = *(const float4*)&cw[d * 4];
    const float4 w1 = *(const float4*)&cw[(d + 1) * 4];
    float a0 = cb[d], a1 = cb[d + 1];
#pragma unroll
    for (int k = 0; k < 4; ++k) {
        int lag = 3 - k;
        if (l >= lag) {
            unsigned v = *(const unsigned*)&xcb[(size_t)(m - lag) * DINNER + d];
            float x0 = bf2f((u16)(v & 0xffff));
            float x1 = bf2f((u16)(v >> 16));
            float wk0 = (&w0.x)[k], wk1 = (&w1.x)[k];
            a0 += x0 * wk0; a1 += x1 * wk1;
        }
    }
    a0 = a0 / (1.f + __expf(-a0));
    a1 = a1 / (1.f + __expf(-a1));
    unsigned pack = (unsigned)f2bf(a0) | ((unsigned)f2bf(a1) << 16);
    *(unsigned*)&ub[idx] = pack;
}

// ---------------------------------------------------------------------------
// Chunked scan pass 1 — one lane per (b,c,d), 16 states in VGPRs.
// CHUNKS=64, CLEN=16 -> 1024 blocks (4 waves/SIMD) for latency hiding.
__global__ __launch_bounds__(256) void scan1_kernel(
    const u16* __restrict__ ub, const float* xdbl,
    const u16* __restrict__ dtb, const float* __restrict__ A_log,
    u16* __restrict__ hfinal, float* __restrict__ dsum)
{
    __shared__ float Bs[CLEN][16];
    const int blk  = blockIdx.x;              // b*256 + c*4 + dblk
    const int dblk = blk & 3;
    const int c    = (blk >> 2) & (CHUNKS - 1);
    const int b    = blk >> 8;
    const int d    = dblk * 256 + threadIdx.x;
    const int mbase = b * L_ + c * CLEN;

    {   // CLEN*16 = 256 entries, one per thread
        int idx = threadIdx.x;
        int tt = idx >> 4, ss = idx & 15;
        Bs[tt][ss] = xdbl[(size_t)(mbase + tt) * 64 + 32 + ss];
    }
    float A[16];
    {
        float4 a4[4];
#pragma unroll
        for (int q = 0; q < 4; ++q) a4[q] = *(const float4*)&A_log[d * 16 + q * 4];
        const float* af = (const float*)a4;
#pragma unroll
        for (int s = 0; s < 16; ++s) A[s] = -__expf(af[s]);
    }
    __syncthreads();

    float h[16];
#pragma unroll
    for (int s = 0; s < 16; ++s) h[s] = 0.f;
    float dts = 0.f;

    for (int t0 = 0; t0 < CLEN; t0 += 8) {
        float dt8[8], u8[8];
#pragma unroll
        for (int j = 0; j < 8; ++j) {
            int m = mbase + t0 + j;
            dt8[j] = bf2f(dtb[(size_t)m * DINNER + d]);
            u8[j]  = bf2f(ub [(size_t)m * DINNER + d]);
        }
#pragma unroll
        for (int j = 0; j < 8; ++j) {
            float dtv = dt8[j], dtu = dtv * u8[j];
            dts += dtv;
            float Bt[16];
#pragma unroll
            for (int q = 0; q < 4; ++q)
                *(float4*)&Bt[q*4] = *(const float4*)&Bs[t0 + j][q*4];
#pragma unroll
            for (int s = 0; s < 16; ++s) {
                float dA = __expf(dtv * A[s]);
                h[s] = dA * h[s] + dtu * Bt[s];
            }
        }
    }
    size_t base = ((size_t)(b * CHUNKS + c) * DINNER + d) * 16;
    s16x8 p0, p1;
#pragma unroll
    for (int s = 0; s < 8; ++s) { p0[s] = (short)f2bf(h[s]); p1[s] = (short)f2bf(h[s+8]); }
    *(s16x8*)&hfinal[base]     = p0;
    *(s16x8*)&hfinal[base + 8] = p1;
    dsum[(size_t)(b * CHUNKS + c) * DINNER + d] = dts;
}

// Pass 2: sequential chunk fix-up (bf16 states, fp32 math).
__global__ __launch_bounds__(256) void scan2_kernel(
    u16* __restrict__ hfinal, const float* __restrict__ dsum,
    const float* __restrict__ A_log)
{
    int t = blockIdx.x * 256 + threadIdx.x;   // 65536 = B_*DINNER*DSTATE
    int s = t & 15, d = (t >> 4) & (DINNER - 1), b = t >> 14;
    float As = -__expf(A_log[d * DSTATE + s]);
    float h = 0.f;
    for (int c0 = 0; c0 < CHUNKS; c0 += 8) {
        float hf8[8], dts8[8];
#pragma unroll
        for (int j = 0; j < 8; ++j) {
            int c = c0 + j;
            size_t i = (size_t)(b * CHUNKS + c) * DINNER + d;
            dts8[j] = dsum[i];
            hf8[j]  = bf2f(hfinal[i * 16 + s]);
        }
#pragma unroll
        for (int j = 0; j < 8; ++j) {
            int c = c0 + j;
            size_t idx = ((size_t)(b * CHUNKS + c) * DINNER + d) * 16 + s;
            hfinal[idx] = f2bf(h);
            h = __expf(As * dts8[j]) * h + hf8[j];
        }
    }
}

// Pass 3: seeded local scan; y = (C.h + u*D)*sz, written bf16.
__global__ __launch_bounds__(256) void scan3_kernel(
    const u16* __restrict__ szb, const u16* __restrict__ ub,
    const float* xdbl, const u16* __restrict__ dtb,
    const float* __restrict__ A_log, const float* __restrict__ Dp,
    const u16* __restrict__ hstart, u16* __restrict__ yb)
{
    __shared__ float Bs[CLEN][16];
    __shared__ float Cs[CLEN][16];
    const int blk  = blockIdx.x;
    const int dblk = blk & 3;
    const int c    = (blk >> 2) & (CHUNKS - 1);
    const int b    = blk >> 8;
    const int d    = dblk * 256 + threadIdx.x;
    const int mbase = b * L_ + c * CLEN;

    {   // CLEN*16 = 256 entries, one per thread
        int idx = threadIdx.x;
        int tt = idx >> 4, ss = idx & 15;
        Bs[tt][ss] = xdbl[(size_t)(mbase + tt) * 64 + 32 + ss];
        Cs[tt][ss] = xdbl[(size_t)(mbase + tt) * 64 + 48 + ss];
    }
    float A[16];
    {
        float4 a4[4];
#pragma unroll
        for (int q = 0; q < 4; ++q) a4[q] = *(const float4*)&A_log[d * 16 + q * 4];
        const float* af = (const float*)a4;
#pragma unroll
        for (int s = 0; s < 16; ++s) A[s] = -__expf(af[s]);
    }
    const float Dval = Dp[d];

    float h[16];
    {
        size_t base = ((size_t)(b * CHUNKS + c) * DINNER + d) * 16;
        s16x8 p0 = *(const s16x8*)&hstart[base];
        s16x8 p1 = *(const s16x8*)&hstart[base + 8];
#pragma unroll
        for (int s = 0; s < 8; ++s) { h[s] = bf2f((u16)p0[s]); h[s+8] = bf2f((u16)p1[s]); }
    }
    __syncthreads();

    for (int t0 = 0; t0 < CLEN; t0 += 8) {
        float dt8[8], u8[8], sz8[8];
#pragma unroll
        for (int j = 0; j < 8; ++j) {
            int m = mbase + t0 + j;
            dt8[j] = bf2f(dtb[(size_t)m * DINNER + d]);
            u8[j]  = bf2f(ub [(size_t)m * DINNER + d]);
            sz8[j] = bf2f(szb[(size_t)m * DINNER + d]);
        }
#pragma unroll
        for (int j = 0; j < 8; ++j) {
            float dtv = dt8[j], dtu = dtv * u8[j];
            float Bt[16], Ct[16];
#pragma unroll
            for (int q = 0; q < 4; ++q) {
                *(float4*)&Bt[q*4] = *(const float4*)&Bs[t0 + j][q*4];
                *(float4*)&Ct[q*4] = *(const float4*)&Cs[t0 + j][q*4];
            }
            float yv = 0.f;
#pragma unroll
            for (int s = 0; s < 16; ++s) {
                float dA = __expf(dtv * A[s]);
                h[s] = dA * h[s] + dtu * Bt[s];
                yv += h[s] * Ct[s];
            }
            int m = mbase + t0 + j;
            yb[(size_t)m * DINNER + d] = f2bf((yv + u8[j] * Dval) * sz8[j]);
        }
    }
}

// ---------------------------------------------------------------------------
// Final LayerNorm over DMODEL=512, reading bf16 h.
__global__ __launch_bounds__(256) void ln_kernel(
    const u16* __restrict__ hb, const float* __restrict__ g,
    const float* __restrict__ bta, float* __restrict__ out)
{
    int m = blockIdx.x;
    size_t base = (size_t)m * DMODEL;
    int t = threadIdx.x;
    float v0 = bf2f(hb[base + t]);
    float v1 = bf2f(hb[base + t + 256]);
    float sum = v0 + v1, sq = v0*v0 + v1*v1;
#pragma unroll
    for (int off = 32; off; off >>= 1) {
        sum += __shfl_down(sum, off);
        sq  += __shfl_down(sq,  off);
    }
    __shared__ float ls[4], lq[4];
    int w = t >> 6;
    if ((t & 63) == 0) { ls[w] = sum; lq[w] = sq; }
    __syncthreads();
    sum = ls[0] + ls[1] + ls[2] + ls[3];
    sq  = lq[0] + lq[1] + lq[2] + lq[3];
    float mu  = sum * (1.f / DMODEL);
    float var = sq * (1.f / DMODEL) - mu * mu;
    float rs  = rsqrtf(var + 1e-5f);
    out[base + t]       = (v0 - mu) * rs * g[t]       + bta[t];
    out[base + t + 256] = (v1 - mu) * rs * g[t + 256] + bta[t + 256];
}

// ---------------------------------------------------------------------------
extern "C" void kernel_launch(void* const* d_in, const int* in_sizes, int n_in,
                              void* d_out, int out_size, void* d_ws, size_t ws_size,
                              hipStream_t stream)
{
    const float* x      = (const float*)d_in[0];
    const float* in_w   = (const float*)d_in[1];
    const float* in_b   = (const float*)d_in[2];
    const float* W_xz   = (const float*)d_in[3];
    const float* conv_w = (const float*)d_in[4];
    const float* conv_b = (const float*)d_in[5];
    const float* W_xp   = (const float*)d_in[6];
    const float* W_dt   = (const float*)d_in[7];
    const float* b_dt   = (const float*)d_in[8];
    const float* A_log  = (const float*)d_in[9];
    const float* D_par  = (const float*)d_in[10];
    const float* W_out  = (const float*)d_in[11];
    const float* ln_g   = (const float*)d_in[12];
    const float* ln_b   = (const float*)d_in[13];
    float* out = (float*)d_out;

    // Workspace layout (floats), total ~19.3 M floats = 77 MB.
    float* ws      = (float*)d_ws;
    float* hbF     = ws;                    // 1 M   : hb bf16 (2M u16)
    float* hfinF   = hbF    + 1048576;      // 2 M   : hfinal/hstart bf16 (4M u16, CHUNKS=64)
    float* xcbF    = hfinF  + 2097152;      // 2 M   : xc bf16
    float* szbF    = xcbF   + 2097152;      // 2 M   : silu(z) bf16
    float* ubF     = szbF   + 2097152;      // 2 M   : u bf16
    float* xdbl    = ubF    + 2097152;      // 256 K : fp32 (B/C in cols 32..63)
    float* dtbF    = xdbl   + 262144;       // 2 M   : dt bf16
    float* ybF     = dtbF   + 2097152;      // 2 M   : y bf16
    float* wxzF    = ybF    + 2097152;      // 2 M   : Wxz bf16, all layers
    float* woutF   = wxzF   + 2097152;      // 1 M   : Wout bf16, all layers
    float* wxpF    = woutF  + 1048576;      // 128 K : Wxp bf16, all layers
    float* wdtF    = wxpF   + 131072;       // 64 K  : Wdt bf16, all layers
    float* dsum    = wdtF   + 65536;        // 256 K : per-chunk dt sums fp32
    float* dtlrF   = dsum   + 262144;       // 64 K  : dt_lr bf16 (4096*32 u16)
    float* xpart   = dtlrF  + 65536;        // 2 M   : xp K-split partials fp32 (8 x 4096 x 64)

    u16* hb     = (u16*)hbF;
    u16* hfinal = (u16*)hfinF;
    u16* xcb  = (u16*)xcbF;
    u16* szb  = (u16*)szbF;
    u16* ub   = (u16*)ubF;
    u16* dtb  = (u16*)dtbF;
    u16* yb   = (u16*)ybF;
    u16* wxzb  = (u16*)wxzF;
    u16* woutb = (u16*)woutF;
    u16* wxpb  = (u16*)wxpF;
    u16* wdtb  = (u16*)wdtF;
    u16* dtlrb = (u16*)dtlrF;

    // One-time weight prep (single dispatch).
    wprep_kernel<<<3264, 256, 0, stream>>>(W_xz, W_out, W_xp, W_dt,
                                           wxzb, woutb, wxpb, wdtb);

    in_proj_kernel<<<MTOT*DMODEL/256, 256, 0, stream>>>(x, in_w, in_b, hb);

    for (int layer = 0; layer < DEPTH_; ++layer) {
        const float* cw    = conv_w + (size_t)layer * DINNER * DCONV;
        const float* cb    = conv_b + (size_t)layer * DINNER;
        const float* bdt   = b_dt   + (size_t)layer * DINNER;
        const float* Alog  = A_log  + (size_t)layer * DINNER * DSTATE;
        const float* Dp    = D_par  + (size_t)layer * DINNER;
        const u16* wxzL    = wxzb  + (size_t)layer * 2048 * DMODEL;
        const u16* woutL   = woutb + (size_t)layer * DMODEL * DINNER;
        const u16* wxpL    = wxpb  + (size_t)layer * 64 * DINNER;
        const u16* wdtL    = wdtb  + (size_t)layer * DINNER * DTRANK;

        // xz GEMM (K=512), fused epilogue: bf16 xc + bf16 silu(z)
        gemm_bf16<128,128,1><<<dim3(2048/128, MTOT/128), 256, 0, stream>>>(
            hb, DMODEL, wxzL, DMODEL, xcb, szb, 0, DMODEL);
        // u = silu(conv(xc) + cb)
        conv_silu_kernel<<<MTOT*DINNER/2/256, 256, 0, stream>>>(xcb, cw, cb, ub);
        // xp GEMM K-split: partials (8 splits x K=128), grid 512 blocks
        gemm_bf16<64,64,6><<<dim3(XPSPLIT, MTOT/64), 256, 0, stream>>>(
            ub, DINNER, wxpL, DINNER, xpart, nullptr, 0, DINNER/XPSPLIT);
        // reduce partials -> dt_lr bf16 + B/C fp32
        xpred_kernel<<<MTOT*16/256, 256, 0, stream>>>(xpart, dtlrb, xdbl);
        // dt = softplus(dt_lr @ Wdt^T + bdt) (M=4096, N=1024, K=32) -> bf16
        gemm_bf16<64,64,4><<<dim3(DINNER/64, MTOT/64), 256, 0, stream>>>(
            dtlrb, DTRANK, wdtL, DTRANK, dtb, (void*)bdt, DINNER, DTRANK);
        // chunked selective scan (bf16 chunk states)
        scan1_kernel<<<B_*CHUNKS*(DINNER/256), 256, 0, stream>>>(ub, xdbl, dtb, Alog, hfinal, dsum);
        scan2_kernel<<<(B_*DINNER*DSTATE)/256, 256, 0, stream>>>(hfinal, dsum, Alog);
        scan3_kernel<<<B_*CHUNKS*(DINNER/256), 256, 0, stream>>>(szb, ub, xdbl, dtb, Alog, Dp, hfinal, yb);
        // h = y @ Wout^T (K=1024), 64x64 tile, direct bf16 epilogue
        gemm_bf16<64,64,2><<<dim3(DMODEL/64, MTOT/64), 256, 0, stream>>>(
            yb, DINNER, woutL, DINNER, hb, nullptr, DMODEL, DINNER);
    }

    ln_kernel<<<MTOT, 256, 0, stream>>>(hb, ln_g, ln_b, out);
}